// Round 13
// baseline (236.190 us; speedup 1.0000x reference)
//
#include <hip/hip_runtime.h>
#include <hip/hip_bf16.h>

#define NN 16384          // nodes
#define NE 262144         // edges
#define N64 (NN * 64)

typedef unsigned short u16;
typedef __attribute__((ext_vector_type(8))) short short8;
typedef __attribute__((ext_vector_type(4))) float f32x4;

__device__ __forceinline__ float us2f(u16 u) {
    union { unsigned int i; float f; } v; v.i = ((unsigned int)u) << 16; return v.f;
}
__device__ __forceinline__ u16 f2us(float x) {   // f32 -> bf16 bits, RNE
    union { float f; unsigned int i; } u; u.f = x;
    unsigned int r = u.i + 0x7FFF + ((u.i >> 16) & 1);
    return (u16)(r >> 16);
}
__device__ __forceinline__ float silu_f(float x) { return x / (1.0f + __expf(-x)); }
__device__ __forceinline__ float ldf(const void* p, long i, int f) {
    return f ? ((const float*)p)[i] : us2f(((const u16*)p)[i]);
}
__device__ __forceinline__ void ld8(const void* p, long v8, int f, float* o) {
    if (f) {
        const f32x4* q = (const f32x4*)p + v8 * 2;
        f32x4 a = q[0], b = q[1];
        o[0] = a[0]; o[1] = a[1]; o[2] = a[2]; o[3] = a[3];
        o[4] = b[0]; o[5] = b[1]; o[6] = b[2]; o[7] = b[3];
    } else {
        short8 s = ((const short8*)p)[v8];
#pragma unroll
        for (int j = 0; j < 8; j++) o[j] = us2f((u16)s[j]);
    }
}
__device__ __forceinline__ void st8(u16* d, const float* o) {
    short8 s;
#pragma unroll
    for (int j = 0; j < 8; j++) s[j] = (short)f2us(o[j]);
    *reinterpret_cast<short8*>(d) = s;
}
// packed bf16x2 atomic add (global_atomic_pk_add_bf16)
__device__ __forceinline__ void atom_pk(u16* addr, float a, float b) {
    unsigned int pk = (unsigned)f2us(a) | ((unsigned)f2us(b) << 16);
    unsafeAtomicAdd(reinterpret_cast<__hip_bfloat162*>(addr),
                    *reinterpret_cast<__hip_bfloat162*>(&pk));
}
// scalar-pipe bf16->f32 for wave-uniform values (shift happens on SALU)
__device__ __forceinline__ float us2f_s(unsigned bits16) {
    union { unsigned int i; float f; } v; v.i = bits16 << 16; return v.f;
}

// ---------------- dtype sniff + cnt/abuf zeroing (one dispatch) ----------------
__global__ void k_sniff(const u16* __restrict__ re, int* __restrict__ flag,
                        int* __restrict__ cnt, f32x4* __restrict__ abufv) {
    int i = blockIdx.x * 256 + threadIdx.x;
    if (i < NN) cnt[i] = 0;
    // zero abuf: 16 MB = 2048 blocks * 256 threads * 32 B
    f32x4 z = 0.0f;
    abufv[(long)i * 2] = z;
    abufv[(long)i * 2 + 1] = z;
    if (blockIdx.x == 0 && threadIdx.x < 64) {
        int t = threadIdx.x;
        int hit = (re[t] >= 0x4000) ? 1 : 0;
        unsigned long long b = __ballot(hit);
        if (t == 0) *flag = (__popcll(b) >= 4) ? 1 : 0;   // 1 => f32 inputs
    }
}

// ---------------- convert all float tensors to bf16 + x1 transpose + hist ------
// Vectorized: big tensors 8 elems/thread (x1: 24/thread -> 3 coalesced plane
// stores); weights scalar.
// Weight layouts (consumed as MFMA B-operands, single short8 fragment loads):
//   c_Wup0/c_Wup1 : [k_out=64][m=64]   c_Rw2 : [k_out=256][m=64]
//   c_Wd0 : [n=128][k'=128]  c_Wd1 : [n=64][k'=128]   k' = chan*2 + part
//     (abuf is pair-interleaved: [node][pair][chan][2], so the down-GEMM K
//      order is chan-major within each output pair)
//   c_Wsc0 : [s][n=128][m=64]  c_Wsc1 : [s][n=64][m=64]
#define SB0 1048576L
#define SB1 4194304L
#define SB2 4456448L
#define SB3 5242880L
#define SB4 7340032L
#define SB5 7344128L
#define SB6 7348224L
#define SB7 7348736L
#define SB8 7365120L
#define SB9 7381504L
#define SB10 7389696L
#define SB11 7422464L
#define SB12 7438848L

__global__ void k_convert(const void* x0, const void* x1, const void* ey0, const void* ey1,
                          const void* re, const void* Wup0, const void* Wup1, const void* Rw1,
                          const void* Rw2, const void* Wd0, const void* Wd1, const void* Wsc0,
                          const void* Wsc1, const int* __restrict__ flag,
                          const int* __restrict__ recv, int* __restrict__ cnt,
                          u16* c_x0, u16* x1T, u16* c_ey0, u16* c_ey1, u16* c_re,
                          u16* c_Wup0, u16* c_Wup1, u16* c_Rw1, u16* c_Rw2,
                          u16* c_Wd0, u16* c_Wd1, u16* c_Wsc0, u16* c_Wsc1) {
    long i = (long)blockIdx.x * 256 + threadIdx.x;
    int f = *flag;
    if (i < NE) atomicAdd(&cnt[recv[i]], 1);          // fused histogram
    if (i < 131072) {
        float o[8]; ld8(x0, i, f, o); st8(c_x0 + i * 8, o);
    } else if (i < 262144) {
        long v = i - 131072;
        int n = (int)(v >> 3), k8 = (int)(v & 7);
        long b8 = (long)n * 24 + (long)k8 * 3;
        float o[24];
        ld8(x1, b8, f, o); ld8(x1, b8 + 1, f, o + 8); ld8(x1, b8 + 2, f, o + 16);
#pragma unroll
        for (int c = 0; c < 3; c++) {
            float t[8];
#pragma unroll
            for (int k = 0; k < 8; k++) t[k] = o[k * 3 + c];
            st8(x1T + (long)c * N64 + (long)n * 64 + k8 * 8, t);
        }
    } else if (i < 294912) {
        long v = i - 262144; float o[8]; ld8(ey0, v, f, o); st8(c_ey0 + v * 8, o);
    } else if (i < 393216) {
        long v = i - 294912; float o[8]; ld8(ey1, v, f, o); st8(c_ey1 + v * 8, o);
    } else if (i < 655360) {
        long v = i - 393216; float o[8]; ld8(re, v, f, o); st8(c_re + v * 8, o);
    } else {
        long t = i - 655360;
        if (t < 4096)       { long r = t >> 6, c = t & 63;
                              c_Wup0[c * 64 + r] = f2us(ldf(Wup0, t, f)); }
        else if (t < 8192)  { t -= 4096; long r = t >> 6, c = t & 63;
                              c_Wup1[c * 64 + r] = f2us(ldf(Wup1, t, f)); }
        else if (t < 8704)  { t -= 8192; c_Rw1[t] = f2us(ldf(Rw1, t, f)); }
        else if (t < 25088) { t -= 8704; long r = t >> 8, c = t & 255;
                              c_Rw2[c * 64 + r] = f2us(ldf(Rw2, t, f)); }
        else if (t < 41472) { t -= 25088; long r = t >> 7, c = t & 127;
                              long kp = ((r & 63) << 1) | (r >> 6);   // pair-interleave
                              c_Wd0[c * 128 + kp] = f2us(ldf(Wd0, t, f)); }
        else if (t < 49664) { t -= 41472; long r = t >> 6, c = t & 63;
                              long kp = ((r & 63) << 1) | (r >> 6);   // pair-interleave
                              c_Wd1[c * 128 + kp] = f2us(ldf(Wd1, t, f)); }
        else if (t < 82432) { t -= 49664; long s = t >> 13, rm = t & 8191;
                              long r = rm >> 7, c = rm & 127;
                              c_Wsc0[s * 8192 + c * 64 + r] = f2us(ldf(Wsc0, t, f)); }
        else                { t -= 82432; long s = t >> 12, rm = t & 4095;
                              long r = rm >> 6, c = rm & 63;
                              c_Wsc1[s * 4096 + c * 64 + r] = f2us(ldf(Wsc1, t, f)); }
    }
}

// ---------------- CSR scan + scatter -------------------------------------------
__global__ void k_scan(const int* __restrict__ cnt, int* __restrict__ offs,
                       int* __restrict__ cursor) {
    __shared__ int sd[256];
    int t = threadIdx.x;
    int base = t * 64;
    const int4* c4 = (const int4*)cnt;
    int loc[64];
#pragma unroll
    for (int i = 0; i < 16; i++) {
        int4 v = c4[t * 16 + i];
        loc[i * 4 + 0] = v.x; loc[i * 4 + 1] = v.y; loc[i * 4 + 2] = v.z; loc[i * 4 + 3] = v.w;
    }
    int sum = 0;
#pragma unroll
    for (int i = 0; i < 64; i++) sum += loc[i];
    sd[t] = sum; __syncthreads();
    for (int off = 1; off < 256; off <<= 1) {
        int v = (t >= off) ? sd[t - off] : 0;
        __syncthreads();
        sd[t] += v;
        __syncthreads();
    }
    int run = sd[t] - sum;
    for (int i = 0; i < 64; i++) {
        offs[base + i] = run; cursor[base + i] = run;
        run += loc[i];
    }
    if (t == 255) offs[NN] = run;
}

// meta.w packs edge id (18 bits) | receiver node (14 bits) -------------------
__global__ void k_scatter(const int* __restrict__ recv, const int* __restrict__ senders,
                          const u16* __restrict__ ey0, const u16* __restrict__ ey1,
                          int* __restrict__ cursor, int4* __restrict__ meta) {
    int e = blockIdx.x * 256 + threadIdx.x;
    int node = recv[e];
    int p = atomicAdd(&cursor[node], 1);
    unsigned y0  = ey0[e];
    unsigned y1x = ey1[(long)e * 3 + 0];
    unsigned y1y = ey1[(long)e * 3 + 1];
    unsigned y1z = ey1[(long)e * 3 + 2];
    int4 m;
    m.x = senders[e];
    m.y = (int)(y0 | (y1x << 16));
    m.z = (int)(y1y | (y1z << 16));
    m.w = (int)((unsigned)e | ((unsigned)node << 18));
    meta[p] = m;
}

// ---------------- linear_up: h[node][64ch][4comp] interleaved bf16 --------------
__global__ void k_up_gemm(const u16* __restrict__ x0, const u16* __restrict__ x1T,
                          const u16* __restrict__ Wup0, const u16* __restrict__ Wup1,
                          u16* __restrict__ h) {
    int inst = blockIdx.y;
    int wv = threadIdx.x >> 6, lane = threadIdx.x & 63;
    int lhi = lane >> 4, llo = lane & 15;
    int mb = blockIdx.x * 256 + wv * 64;
    const u16* B = (inst == 0) ? Wup0 : Wup1;     // transposed [k_out=64][m=64]
    const u16* A = (inst == 0) ? x0 : (x1T + (long)(inst - 1) * N64);

    short8 bfr[4][2];
#pragma unroll
    for (int t = 0; t < 4; t++)
#pragma unroll
        for (int s = 0; s < 2; s++)
            bfr[t][s] = *reinterpret_cast<const short8*>(B + (long)(t * 16 + llo) * 64 + s * 32 + lhi * 8);

    f32x4 acc[4][4];
#pragma unroll
    for (int i = 0; i < 4; i++)
#pragma unroll
        for (int t = 0; t < 4; t++) acc[i][t] = 0.0f;

#pragma unroll
    for (int s = 0; s < 2; s++) {
        short8 af[4];
#pragma unroll
        for (int i = 0; i < 4; i++)
            af[i] = *reinterpret_cast<const short8*>(A + (long)(mb + i * 16 + llo) * 64 + s * 32 + lhi * 8);
#pragma unroll
        for (int i = 0; i < 4; i++)
#pragma unroll
            for (int t = 0; t < 4; t++)
                acc[i][t] = __builtin_amdgcn_mfma_f32_16x16x32_bf16(af[i], bfr[t][s], acc[i][t], 0, 0, 0);
    }
#pragma unroll
    for (int i = 0; i < 4; i++)
#pragma unroll
        for (int t = 0; t < 4; t++)
#pragma unroll
            for (int r = 0; r < 4; r++)
                h[(long)(mb + i * 16 + lhi * 4 + r) * 256 + (t * 16 + llo) * 4 + inst] =
                    f2us(acc[i][t][r] * 0.125f);
}

// ---------------- fused radial MLP + tensor-product gather (CSR-ordered) --------
// Round-12 structure (RROW 268, aliased hid, meta-in-LDS, 16-deep h preload,
// XCD-chunked swizzle, pk-bf16 atomic flush) + wave-uniform scalarization:
// meta fields are identical across the wave (uniform LDS read), so node id,
// y-values, and h-row base addresses are hoisted to the scalar pipe via
// readfirstlane -> SALU shifts + SGPR-base loads, cutting phase-C VALU work.
#define RROW 268
__global__ void __launch_bounds__(256, 4)
k_edge(const u16* __restrict__ re, const u16* __restrict__ Rw1,
       const u16* __restrict__ Rw2, const int4* __restrict__ meta,
       const u16* __restrict__ h, u16* __restrict__ abuf) {
    __shared__ u16 w_lds[64 * RROW];          // 34304 B; hid aliased below
    __shared__ int4 meta_s[64];               // 1024 B
    u16 (*hid_s)[72] = reinterpret_cast<u16 (*)[72]>(w_lds);

    int tid = threadIdx.x;
    int wv = tid >> 6, lane = tid & 63, lhi = lane >> 4, llo = lane & 15;
    int bid = blockIdx.x;
    int nchunk = gridDim.x >> 3;              // 512 when grid = 4096
    int cblk = (bid & 7) * nchunk + (bid >> 3);   // XCD-chunked, bijective
    int p0 = cblk * 64;

    if (tid < 64) meta_s[tid] = meta[p0 + tid];
    __syncthreads();

    // ---- phase A: radial hidden layer for this block's 64 CSR slots ----------
    {
        int el = tid >> 2;
        int jb = (tid & 3) * 16;
        int e = meta_s[el].w & 0x3FFFF;
        short8 r8 = *reinterpret_cast<const short8*>(re + (long)e * 8);
        float rr[8];
#pragma unroll
        for (int r = 0; r < 8; r++) rr[r] = us2f((u16)r8[r]);
        float hv[16];
#pragma unroll
        for (int q = 0; q < 2; q++) {
            short8 w8 = *reinterpret_cast<const short8*>(Rw1 + jb + q * 8);
#pragma unroll
            for (int j = 0; j < 8; j++) hv[q * 8 + j] = rr[0] * us2f((u16)w8[j]);
        }
#pragma unroll
        for (int r = 1; r < 8; r++) {
#pragma unroll
            for (int q = 0; q < 2; q++) {
                short8 w8 = *reinterpret_cast<const short8*>(Rw1 + (long)r * 64 + jb + q * 8);
#pragma unroll
                for (int j = 0; j < 8; j++) hv[q * 8 + j] += rr[r] * us2f((u16)w8[j]);
            }
        }
#pragma unroll
        for (int q = 0; q < 4; q++) {
            ushort4 pk;
            pk.x = f2us(silu_f(hv[q * 4 + 0] * 0.35355339059327373f));
            pk.y = f2us(silu_f(hv[q * 4 + 1] * 0.35355339059327373f));
            pk.z = f2us(silu_f(hv[q * 4 + 2] * 0.35355339059327373f));
            pk.w = f2us(silu_f(hv[q * 4 + 3] * 0.35355339059327373f));
            *reinterpret_cast<ushort4*>(&hid_s[el][jb + q * 4]) = pk;
        }
    }
    __syncthreads();

    // ---- phase B: hid[64x64] @ Rw2T -> w_lds[64 slots][256] -------------------
    {
        short8 bfr[4][2];
#pragma unroll
        for (int t = 0; t < 4; t++)
#pragma unroll
            for (int s = 0; s < 2; s++)
                bfr[t][s] = *reinterpret_cast<const short8*>(
                    Rw2 + (long)(wv * 64 + t * 16 + llo) * 64 + s * 32 + lhi * 8);
        f32x4 acc[4][4];
#pragma unroll
        for (int i = 0; i < 4; i++)
#pragma unroll
            for (int t = 0; t < 4; t++) acc[i][t] = 0.0f;
#pragma unroll
        for (int s = 0; s < 2; s++) {
            short8 af[4];
#pragma unroll
            for (int i = 0; i < 4; i++)
                af[i] = *reinterpret_cast<const short8*>(&hid_s[i * 16 + llo][s * 32 + lhi * 8]);
#pragma unroll
            for (int i = 0; i < 4; i++)
#pragma unroll
                for (int t = 0; t < 4; t++)
                    acc[i][t] = __builtin_amdgcn_mfma_f32_16x16x32_bf16(af[i], bfr[t][s], acc[i][t], 0, 0, 0);
        }
        __syncthreads();     // all hid reads done; safe to overwrite region with w
#pragma unroll
        for (int i = 0; i < 4; i++)
#pragma unroll
            for (int t = 0; t < 4; t++)
#pragma unroll
                for (int r = 0; r < 4; r++)
                    w_lds[(i * 16 + lhi * 4 + r) * RROW + wv * 64 + t * 16 + llo] =
                        f2us(acc[i][t][r] * 0.125f);
    }
    __syncthreads();

    // ---- phase C: 16-deep h preload (SGPR base) + pk-bf16 atomic reduction ----
    {
        const float qn = 0.25f;                 // 1/sqrt(avg_neigh)
        const float rs3 = 0.57735026918962576f; // 1/sqrt(3)
        int l = lane;
        int base = wv * 16;

        ushort4 hreg[16];
#pragma unroll
        for (int ss = 0; ss < 16; ss++) {
            long sx = (long)__builtin_amdgcn_readfirstlane(meta_s[base + ss].x);
            hreg[ss] = *reinterpret_cast<const ushort4*>(h + sx * 256 + l * 4);
        }

        float acc[8];
#pragma unroll
        for (int r = 0; r < 8; r++) acc[r] = 0.f;
        int cur = -1;

#pragma unroll
        for (int ss = 0; ss < 16; ss++) {
            unsigned my = (unsigned)__builtin_amdgcn_readfirstlane(meta_s[base + ss].y);
            unsigned mz = (unsigned)__builtin_amdgcn_readfirstlane(meta_s[base + ss].z);
            unsigned mw = (unsigned)__builtin_amdgcn_readfirstlane(meta_s[base + ss].w);
            int node = (int)(mw >> 18);
            if (node != cur) {                       // wave-uniform branch (SCC)
                if (cur >= 0) {
                    u16* dst = abuf + (long)cur * 512 + l * 2;
                    atom_pk(dst,       acc[0] * qn, acc[1] * qn * rs3);
                    atom_pk(dst + 128, acc[2] * qn, acc[3] * qn);
                    atom_pk(dst + 256, acc[4] * qn, acc[5] * qn);
                    atom_pk(dst + 384, acc[6] * qn, acc[7] * qn);
                }
                cur = node;
#pragma unroll
                for (int r = 0; r < 8; r++) acc[r] = 0.f;
            }
            int sl = base + ss;
            float w0 = us2f(w_lds[sl * RROW + l]);
            float w1 = us2f(w_lds[sl * RROW + 64 + l]);
            float w2 = us2f(w_lds[sl * RROW + 128 + l]);
            float w3 = us2f(w_lds[sl * RROW + 192 + l]);
            float y0  = us2f_s(my & 0xffffu);       // SALU shift, SGPR operand
            float y1x = us2f_s(my >> 16);
            float y1y = us2f_s(mz & 0xffffu);
            float y1z = us2f_s(mz >> 16);
            float s0 = us2f(hreg[ss].x), s1x = us2f(hreg[ss].y);
            float s1y = us2f(hreg[ss].z), s1z = us2f(hreg[ss].w);
            acc[0] += w0 * s0 * y0;
            acc[1] += w1 * (s1x * y1x + s1y * y1y + s1z * y1z);
            acc[2] += w2 * s0 * y1x;  acc[3] += w3 * s1x * y0;
            acc[4] += w2 * s0 * y1y;  acc[5] += w3 * s1y * y0;
            acc[6] += w2 * s0 * y1z;  acc[7] += w3 * s1z * y0;
        }
        {
            u16* dst = abuf + (long)cur * 512 + l * 2;
            atom_pk(dst,       acc[0] * qn, acc[1] * qn * rs3);
            atom_pk(dst + 128, acc[2] * qn, acc[3] * qn);
            atom_pk(dst + 256, acc[4] * qn, acc[5] * qn);
            atom_pk(dst + 384, acc[6] * qn, acc[7] * qn);
        }
    }
}

// ---------------- linear_down + species sc + gate (MFMA) ------------------------
// Block = 32 nodes, 5 waves: wave g = output group {scal, gate, vx, vy, vz}.
// abuf is pair-interleaved bf16: A-fragments load directly as short8; the
// matching K-permutation is baked into c_Wd0/c_Wd1 (k' = chan*2 + part).
#define DN 32
__global__ void __launch_bounds__(320, 3)
k_down(const u16* __restrict__ abuf, const u16* __restrict__ x0,
       const u16* __restrict__ x1T, const int* __restrict__ species,
       const u16* __restrict__ Wd0T, const u16* __restrict__ Wd1T,
       const u16* __restrict__ Wsc0T, const u16* __restrict__ Wsc1T,
       float* __restrict__ out) {
    __shared__ float gate_s[DN][65];
    __shared__ float vec_s[DN * 192];       // raw f1 in output order [row][col*3+c]
    __shared__ int sp_s[DN];
    int tid = threadIdx.x;
    int g = tid >> 6;
    int lane = tid & 63, lhi = lane >> 4, llo = lane & 15;
    int node0 = blockIdx.x * DN;
    if (tid < DN) sp_s[tid] = species[node0 + tid];
    __syncthreads();

    const u16* Ad; const u16* BdT; int bcol;
    const u16* As; const u16* BsT; int sstr;
    if (g <= 1) { Ad = abuf; BdT = Wd0T; bcol = g * 64; As = x0; BsT = Wsc0T; sstr = 8192; }
    else        { Ad = abuf + (g - 1) * 128; BdT = Wd1T; bcol = 0;
                  As = x1T + (long)(g - 2) * N64; BsT = Wsc1T; sstr = 4096; }

    const float inv2 = 0.08838834764831845f;  // 1/sqrt(128)
    const float inv  = 0.125f;                // 1/sqrt(64)

    // ---- self-connection phase: all species, row-select -----------------------
    short8 a2[DN / 16][2];
#pragma unroll
    for (int rt = 0; rt < DN / 16; rt++)
#pragma unroll
        for (int ks = 0; ks < 2; ks++)
            a2[rt][ks] = *reinterpret_cast<const short8*>(
                As + (long)(node0 + rt * 16 + llo) * 64 + ks * 32 + lhi * 8);

    f32x4 res[DN / 16][4];
#pragma unroll
    for (int rt = 0; rt < DN / 16; rt++)
#pragma unroll
        for (int ct = 0; ct < 4; ct++) res[rt][ct] = 0.0f;

    for (int s = 0; s < 4; s++) {
        short8 bs[4][2];
#pragma unroll
        for (int ct = 0; ct < 4; ct++)
#pragma unroll
            for (int ks = 0; ks < 2; ks++)
                bs[ct][ks] = *reinterpret_cast<const short8*>(
                    BsT + (long)s * sstr + (long)(bcol + ct * 16 + llo) * 64 + ks * 32 + lhi * 8);
#pragma unroll
        for (int rt = 0; rt < DN / 16; rt++) {
            f32x4 accs[4];
#pragma unroll
            for (int ct = 0; ct < 4; ct++) accs[ct] = 0.0f;
#pragma unroll
            for (int ks = 0; ks < 2; ks++)
#pragma unroll
                for (int ct = 0; ct < 4; ct++)
                    accs[ct] = __builtin_amdgcn_mfma_f32_16x16x32_bf16(a2[rt][ks], bs[ct][ks], accs[ct], 0, 0, 0);
#pragma unroll
            for (int r = 0; r < 4; r++) {
                int sp = sp_s[rt * 16 + lhi * 4 + r];
                if (sp == s)
#pragma unroll
                    for (int ct = 0; ct < 4; ct++) res[rt][ct][r] = accs[ct][r];
            }
        }
    }

    // ---- linear_down phase -----------------------------------------------------
    short8 bd[4][4];
#pragma unroll
    for (int ct = 0; ct < 4; ct++)
#pragma unroll
        for (int ks = 0; ks < 4; ks++)
            bd[ct][ks] = *reinterpret_cast<const short8*>(
                BdT + (long)(bcol + ct * 16 + llo) * 128 + ks * 32 + lhi * 8);

#pragma unroll
    for (int rt = 0; rt < DN / 16; rt++) {
        f32x4 accd[4];
#pragma unroll
        for (int ct = 0; ct < 4; ct++) accd[ct] = 0.0f;
#pragma unroll
        for (int ks = 0; ks < 4; ks++) {
            short8 a = *reinterpret_cast<const short8*>(
                Ad + (long)(node0 + rt * 16 + llo) * 512 + ks * 32 + lhi * 8);
#pragma unroll
            for (int ct = 0; ct < 4; ct++)
                accd[ct] = __builtin_amdgcn_mfma_f32_16x16x32_bf16(a, bd[ct][ks], accd[ct], 0, 0, 0);
        }
#pragma unroll
        for (int ct = 0; ct < 4; ct++)
#pragma unroll
            for (int r = 0; r < 4; r++) {
                float fvv = 0.5f * (accd[ct][r] * inv2 + res[rt][ct][r] * inv);
                int row = rt * 16 + lhi * 4 + r;
                int col = ct * 16 + llo;
                if (g == 0) {
                    out[(long)(node0 + row) * 64 + col] = silu_f(fvv);
                } else if (g == 1) {
                    gate_s[row][col] = silu_f(fvv);
                } else {
                    vec_s[row * 192 + col * 3 + (g - 2)] = fvv;
                }
            }
    }
    __syncthreads();

    // ---- cooperative coalesced vector store (gate applied here) ---------------
    {
        float* vout = out + (long)N64 + (long)node0 * 192;
        for (int q4 = tid; q4 < DN * 48; q4 += 320) {
            int q = q4 * 4;
            int row = q4 / 48;                // 48 float4 per node row
            int rem = q - row * 192;
            f32x4 v = *reinterpret_cast<const f32x4*>(&vec_s[q]);
#pragma unroll
            for (int e = 0; e < 4; e++) v[e] *= gate_s[row][(rem + e) / 3];
            *reinterpret_cast<f32x4*>(vout + q) = v;
        }
    }
}

// ---------------- host launch --------------------------------------------------
extern "C" void kernel_launch(void* const* d_in, const int* in_sizes, int n_in,
                              void* d_out, int out_size, void* d_ws, size_t ws_size,
                              hipStream_t stream) {
    const int* senders   = (const int*)d_in[5];
    const int* receivers = (const int*)d_in[6];
    const int* species   = (const int*)d_in[7];
    float* out = (float*)d_out;

    char* ws = (char*)d_ws;
    size_t o = 0;
    auto alloc = [&](size_t bytes) { size_t p = o; o = (o + bytes + 255) & ~255UL; return p; };
    int* flag   = (int*)(ws + alloc(4));
    int* cnt    = (int*)(ws + alloc((size_t)NN * 4));
    int* offs   = (int*)(ws + alloc((size_t)(NN + 1) * 4));
    int* cursor = (int*)(ws + alloc((size_t)NN * 4));
    int4* meta  = (int4*)(ws + alloc((size_t)NE * 16));
    u16* c_x0   = (u16*)(ws + alloc(SB0 * 2));
    u16* x1T    = (u16*)(ws + alloc((size_t)3 * N64 * 2));
    u16* c_ey0  = (u16*)(ws + alloc((SB2 - SB1) * 2));
    u16* c_ey1  = (u16*)(ws + alloc((SB3 - SB2) * 2));
    u16* c_re   = (u16*)(ws + alloc((SB4 - SB3) * 2));
    u16* c_Wup0 = (u16*)(ws + alloc((SB5 - SB4) * 2));
    u16* c_Wup1 = (u16*)(ws + alloc((SB6 - SB5) * 2));
    u16* c_Rw1  = (u16*)(ws + alloc((SB7 - SB6) * 2));
    u16* c_Rw2  = (u16*)(ws + alloc((SB8 - SB7) * 2));
    u16* c_Wd0  = (u16*)(ws + alloc((SB9 - SB8) * 2));
    u16* c_Wd1  = (u16*)(ws + alloc((SB10 - SB9) * 2));
    u16* c_Wsc0 = (u16*)(ws + alloc((SB11 - SB10) * 2));
    u16* c_Wsc1 = (u16*)(ws + alloc((SB12 - SB11) * 2));
    u16* h      = (u16*)(ws + alloc((size_t)NN * 256 * 2));   // [node][64][4]
    u16* abuf   = (u16*)(ws + alloc((size_t)NN * 512 * 2));   // [node][4pair][64][2] bf16

    k_sniff<<<2048, 256, 0, stream>>>((const u16*)d_in[4], flag, cnt, (f32x4*)abuf);
    k_convert<<<2946, 256, 0, stream>>>(d_in[0], d_in[1], d_in[2], d_in[3], d_in[4],
        d_in[8], d_in[9], d_in[10], d_in[11], d_in[12], d_in[13], d_in[14], d_in[15],
        flag, receivers, cnt,
        c_x0, x1T, c_ey0, c_ey1, c_re,
        c_Wup0, c_Wup1, c_Rw1, c_Rw2, c_Wd0, c_Wd1, c_Wsc0, c_Wsc1);
    k_scan<<<1, 256, 0, stream>>>(cnt, offs, cursor);
    k_scatter<<<NE / 256, 256, 0, stream>>>(receivers, senders, c_ey0, c_ey1,
                                            cursor, meta);

    k_up_gemm<<<dim3(NN / 256, 4), 256, 0, stream>>>(c_x0, x1T, c_Wup0, c_Wup1, h);

    k_edge<<<NE / 64, 256, 0, stream>>>(c_re, c_Rw1, c_Rw2, meta, h, abuf);

    k_down<<<NN / DN, 320, 0, stream>>>(abuf, c_x0, x1T, species,
                                        c_Wd0, c_Wd1, c_Wsc0, c_Wsc1, out);
}

// Round 15
// 232.224 us; speedup vs baseline: 1.0171x; 1.0171x over previous
//
#include <hip/hip_runtime.h>
#include <hip/hip_bf16.h>

#define NN 16384          // nodes
#define NE 262144         // edges
#define N64 (NN * 64)

typedef unsigned short u16;
typedef __attribute__((ext_vector_type(8))) short short8;
typedef __attribute__((ext_vector_type(4))) float f32x4;

__device__ __forceinline__ float us2f(u16 u) {
    union { unsigned int i; float f; } v; v.i = ((unsigned int)u) << 16; return v.f;
}
__device__ __forceinline__ u16 f2us(float x) {   // f32 -> bf16 bits, RNE
    union { float f; unsigned int i; } u; u.f = x;
    unsigned int r = u.i + 0x7FFF + ((u.i >> 16) & 1);
    return (u16)(r >> 16);
}
__device__ __forceinline__ float silu_f(float x) { return x / (1.0f + __expf(-x)); }
__device__ __forceinline__ float ldf(const void* p, long i, int f) {
    return f ? ((const float*)p)[i] : us2f(((const u16*)p)[i]);
}
__device__ __forceinline__ void ld8(const void* p, long v8, int f, float* o) {
    if (f) {
        const f32x4* q = (const f32x4*)p + v8 * 2;
        f32x4 a = q[0], b = q[1];
        o[0] = a[0]; o[1] = a[1]; o[2] = a[2]; o[3] = a[3];
        o[4] = b[0]; o[5] = b[1]; o[6] = b[2]; o[7] = b[3];
    } else {
        short8 s = ((const short8*)p)[v8];
#pragma unroll
        for (int j = 0; j < 8; j++) o[j] = us2f((u16)s[j]);
    }
}
__device__ __forceinline__ void st8(u16* d, const float* o) {
    short8 s;
#pragma unroll
    for (int j = 0; j < 8; j++) s[j] = (short)f2us(o[j]);
    *reinterpret_cast<short8*>(d) = s;
}
// packed bf16x2 atomic add (global_atomic_pk_add_bf16)
__device__ __forceinline__ void atom_pk(u16* addr, float a, float b) {
    unsigned int pk = (unsigned)f2us(a) | ((unsigned)f2us(b) << 16);
    unsafeAtomicAdd(reinterpret_cast<__hip_bfloat162*>(addr),
                    *reinterpret_cast<__hip_bfloat162*>(&pk));
}
// scalar-pipe bf16->f32 for wave-uniform values (shift happens on SALU)
__device__ __forceinline__ float us2f_s(unsigned bits16) {
    union { unsigned int i; float f; } v; v.i = bits16 << 16; return v.f;
}

// ---------------- dtype sniff + cnt/abuf zeroing (one dispatch) ----------------
__global__ void k_sniff(const u16* __restrict__ re, int* __restrict__ flag,
                        int* __restrict__ cnt, f32x4* __restrict__ abufv) {
    int i = blockIdx.x * 256 + threadIdx.x;
    if (i < NN) cnt[i] = 0;
    // zero abuf: 16 MB = 2048 blocks * 256 threads * 32 B
    f32x4 z = 0.0f;
    abufv[(long)i * 2] = z;
    abufv[(long)i * 2 + 1] = z;
    if (blockIdx.x == 0 && threadIdx.x < 64) {
        int t = threadIdx.x;
        int hit = (re[t] >= 0x4000) ? 1 : 0;
        unsigned long long b = __ballot(hit);
        if (t == 0) *flag = (__popcll(b) >= 4) ? 1 : 0;   // 1 => f32 inputs
    }
}

// ---------------- convert all float tensors to bf16 + x1 transpose + hist ------
// Vectorized: big tensors 8 elems/thread (x1: 24/thread -> 3 coalesced plane
// stores); weights scalar.
// Weight layouts (consumed as MFMA B-operands, single short8 fragment loads):
//   c_Wup0/c_Wup1 : [k_out=64][m=64]   c_Rw2 : [k_out=256][m=64]
//   c_Wd0 : [n=128][k'=128]  c_Wd1 : [n=64][k'=128]   k' = chan*2 + part
//     (abuf is pair-interleaved: [node][pair][chan][2], so the down-GEMM K
//      order is chan-major within each output pair)
//   c_Wsc0 : [s][n=128][m=64]  c_Wsc1 : [s][n=64][m=64]
#define SB0 1048576L
#define SB1 4194304L
#define SB2 4456448L
#define SB3 5242880L
#define SB4 7340032L
#define SB5 7344128L
#define SB6 7348224L
#define SB7 7348736L
#define SB8 7365120L
#define SB9 7381504L
#define SB10 7389696L
#define SB11 7422464L
#define SB12 7438848L

__global__ void k_convert(const void* x0, const void* x1, const void* ey0, const void* ey1,
                          const void* re, const void* Wup0, const void* Wup1, const void* Rw1,
                          const void* Rw2, const void* Wd0, const void* Wd1, const void* Wsc0,
                          const void* Wsc1, const int* __restrict__ flag,
                          const int* __restrict__ recv, int* __restrict__ cnt,
                          u16* c_x0, u16* x1T, u16* c_ey0, u16* c_ey1, u16* c_re,
                          u16* c_Wup0, u16* c_Wup1, u16* c_Rw1, u16* c_Rw2,
                          u16* c_Wd0, u16* c_Wd1, u16* c_Wsc0, u16* c_Wsc1) {
    long i = (long)blockIdx.x * 256 + threadIdx.x;
    int f = *flag;
    if (i < NE) atomicAdd(&cnt[recv[i]], 1);          // fused histogram
    if (i < 131072) {
        float o[8]; ld8(x0, i, f, o); st8(c_x0 + i * 8, o);
    } else if (i < 262144) {
        long v = i - 131072;
        int n = (int)(v >> 3), k8 = (int)(v & 7);
        long b8 = (long)n * 24 + (long)k8 * 3;
        float o[24];
        ld8(x1, b8, f, o); ld8(x1, b8 + 1, f, o + 8); ld8(x1, b8 + 2, f, o + 16);
#pragma unroll
        for (int c = 0; c < 3; c++) {
            float t[8];
#pragma unroll
            for (int k = 0; k < 8; k++) t[k] = o[k * 3 + c];
            st8(x1T + (long)c * N64 + (long)n * 64 + k8 * 8, t);
        }
    } else if (i < 294912) {
        long v = i - 262144; float o[8]; ld8(ey0, v, f, o); st8(c_ey0 + v * 8, o);
    } else if (i < 393216) {
        long v = i - 294912; float o[8]; ld8(ey1, v, f, o); st8(c_ey1 + v * 8, o);
    } else if (i < 655360) {
        long v = i - 393216; float o[8]; ld8(re, v, f, o); st8(c_re + v * 8, o);
    } else {
        long t = i - 655360;
        if (t < 4096)       { long r = t >> 6, c = t & 63;
                              c_Wup0[c * 64 + r] = f2us(ldf(Wup0, t, f)); }
        else if (t < 8192)  { t -= 4096; long r = t >> 6, c = t & 63;
                              c_Wup1[c * 64 + r] = f2us(ldf(Wup1, t, f)); }
        else if (t < 8704)  { t -= 8192; c_Rw1[t] = f2us(ldf(Rw1, t, f)); }
        else if (t < 25088) { t -= 8704; long r = t >> 8, c = t & 255;
                              c_Rw2[c * 64 + r] = f2us(ldf(Rw2, t, f)); }
        else if (t < 41472) { t -= 25088; long r = t >> 7, c = t & 127;
                              long kp = ((r & 63) << 1) | (r >> 6);   // pair-interleave
                              c_Wd0[c * 128 + kp] = f2us(ldf(Wd0, t, f)); }
        else if (t < 49664) { t -= 41472; long r = t >> 6, c = t & 63;
                              long kp = ((r & 63) << 1) | (r >> 6);   // pair-interleave
                              c_Wd1[c * 128 + kp] = f2us(ldf(Wd1, t, f)); }
        else if (t < 82432) { t -= 49664; long s = t >> 13, rm = t & 8191;
                              long r = rm >> 7, c = rm & 127;
                              c_Wsc0[s * 8192 + c * 64 + r] = f2us(ldf(Wsc0, t, f)); }
        else                { t -= 82432; long s = t >> 12, rm = t & 4095;
                              long r = rm >> 6, c = rm & 63;
                              c_Wsc1[s * 4096 + c * 64 + r] = f2us(ldf(Wsc1, t, f)); }
    }
}

// ---------------- CSR scan + scatter -------------------------------------------
__global__ void k_scan(const int* __restrict__ cnt, int* __restrict__ offs,
                       int* __restrict__ cursor) {
    __shared__ int sd[256];
    int t = threadIdx.x;
    int base = t * 64;
    const int4* c4 = (const int4*)cnt;
    int loc[64];
#pragma unroll
    for (int i = 0; i < 16; i++) {
        int4 v = c4[t * 16 + i];
        loc[i * 4 + 0] = v.x; loc[i * 4 + 1] = v.y; loc[i * 4 + 2] = v.z; loc[i * 4 + 3] = v.w;
    }
    int sum = 0;
#pragma unroll
    for (int i = 0; i < 64; i++) sum += loc[i];
    sd[t] = sum; __syncthreads();
    for (int off = 1; off < 256; off <<= 1) {
        int v = (t >= off) ? sd[t - off] : 0;
        __syncthreads();
        sd[t] += v;
        __syncthreads();
    }
    int run = sd[t] - sum;
    for (int i = 0; i < 64; i++) {
        offs[base + i] = run; cursor[base + i] = run;
        run += loc[i];
    }
    if (t == 255) offs[NN] = run;
}

// meta.w packs edge id (18 bits) | receiver node (14 bits) -------------------
__global__ void k_scatter(const int* __restrict__ recv, const int* __restrict__ senders,
                          const u16* __restrict__ ey0, const u16* __restrict__ ey1,
                          int* __restrict__ cursor, int4* __restrict__ meta) {
    int e = blockIdx.x * 256 + threadIdx.x;
    int node = recv[e];
    int p = atomicAdd(&cursor[node], 1);
    unsigned y0  = ey0[e];
    unsigned y1x = ey1[(long)e * 3 + 0];
    unsigned y1y = ey1[(long)e * 3 + 1];
    unsigned y1z = ey1[(long)e * 3 + 2];
    int4 m;
    m.x = senders[e];
    m.y = (int)(y0 | (y1x << 16));
    m.z = (int)(y1y | (y1z << 16));
    m.w = (int)((unsigned)e | ((unsigned)node << 18));
    meta[p] = m;
}

// ---------------- linear_up: h[node][64ch][4comp] interleaved bf16 --------------
__global__ void k_up_gemm(const u16* __restrict__ x0, const u16* __restrict__ x1T,
                          const u16* __restrict__ Wup0, const u16* __restrict__ Wup1,
                          u16* __restrict__ h) {
    int inst = blockIdx.y;
    int wv = threadIdx.x >> 6, lane = threadIdx.x & 63;
    int lhi = lane >> 4, llo = lane & 15;
    int mb = blockIdx.x * 256 + wv * 64;
    const u16* B = (inst == 0) ? Wup0 : Wup1;     // transposed [k_out=64][m=64]
    const u16* A = (inst == 0) ? x0 : (x1T + (long)(inst - 1) * N64);

    short8 bfr[4][2];
#pragma unroll
    for (int t = 0; t < 4; t++)
#pragma unroll
        for (int s = 0; s < 2; s++)
            bfr[t][s] = *reinterpret_cast<const short8*>(B + (long)(t * 16 + llo) * 64 + s * 32 + lhi * 8);

    f32x4 acc[4][4];
#pragma unroll
    for (int i = 0; i < 4; i++)
#pragma unroll
        for (int t = 0; t < 4; t++) acc[i][t] = 0.0f;

#pragma unroll
    for (int s = 0; s < 2; s++) {
        short8 af[4];
#pragma unroll
        for (int i = 0; i < 4; i++)
            af[i] = *reinterpret_cast<const short8*>(A + (long)(mb + i * 16 + llo) * 64 + s * 32 + lhi * 8);
#pragma unroll
        for (int i = 0; i < 4; i++)
#pragma unroll
            for (int t = 0; t < 4; t++)
                acc[i][t] = __builtin_amdgcn_mfma_f32_16x16x32_bf16(af[i], bfr[t][s], acc[i][t], 0, 0, 0);
    }
#pragma unroll
    for (int i = 0; i < 4; i++)
#pragma unroll
        for (int t = 0; t < 4; t++)
#pragma unroll
            for (int r = 0; r < 4; r++)
                h[(long)(mb + i * 16 + lhi * 4 + r) * 256 + (t * 16 + llo) * 4 + inst] =
                    f2us(acc[i][t][r] * 0.125f);
}

// ---------------- fused radial MLP + tensor-product gather (CSR-ordered) --------
// Verified round-13 configuration: RROW 268 (row holds 256 weights + pad;
// conflict-free phase-B stores), aliased hid, meta-in-LDS, 16-deep h preload,
// XCD-chunked swizzle, pk-bf16 atomic flush, wave-uniform scalarization.
#define RROW 268
__global__ void __launch_bounds__(256, 4)
k_edge(const u16* __restrict__ re, const u16* __restrict__ Rw1,
       const u16* __restrict__ Rw2, const int4* __restrict__ meta,
       const u16* __restrict__ h, u16* __restrict__ abuf) {
    __shared__ u16 w_lds[64 * RROW];          // 34304 B; hid aliased below
    __shared__ int4 meta_s[64];               // 1024 B
    u16 (*hid_s)[72] = reinterpret_cast<u16 (*)[72]>(w_lds);

    int tid = threadIdx.x;
    int wv = tid >> 6, lane = tid & 63, lhi = lane >> 4, llo = lane & 15;
    int bid = blockIdx.x;
    int nchunk = gridDim.x >> 3;              // 512 when grid = 4096
    int cblk = (bid & 7) * nchunk + (bid >> 3);   // XCD-chunked, bijective
    int p0 = cblk * 64;

    if (tid < 64) meta_s[tid] = meta[p0 + tid];
    __syncthreads();

    // ---- phase A: radial hidden layer for this block's 64 CSR slots ----------
    {
        int el = tid >> 2;
        int jb = (tid & 3) * 16;
        int e = meta_s[el].w & 0x3FFFF;
        short8 r8 = *reinterpret_cast<const short8*>(re + (long)e * 8);
        float rr[8];
#pragma unroll
        for (int r = 0; r < 8; r++) rr[r] = us2f((u16)r8[r]);
        float hv[16];
#pragma unroll
        for (int q = 0; q < 2; q++) {
            short8 w8 = *reinterpret_cast<const short8*>(Rw1 + jb + q * 8);
#pragma unroll
            for (int j = 0; j < 8; j++) hv[q * 8 + j] = rr[0] * us2f((u16)w8[j]);
        }
#pragma unroll
        for (int r = 1; r < 8; r++) {
#pragma unroll
            for (int q = 0; q < 2; q++) {
                short8 w8 = *reinterpret_cast<const short8*>(Rw1 + (long)r * 64 + jb + q * 8);
#pragma unroll
                for (int j = 0; j < 8; j++) hv[q * 8 + j] += rr[r] * us2f((u16)w8[j]);
            }
        }
#pragma unroll
        for (int q = 0; q < 4; q++) {
            ushort4 pk;
            pk.x = f2us(silu_f(hv[q * 4 + 0] * 0.35355339059327373f));
            pk.y = f2us(silu_f(hv[q * 4 + 1] * 0.35355339059327373f));
            pk.z = f2us(silu_f(hv[q * 4 + 2] * 0.35355339059327373f));
            pk.w = f2us(silu_f(hv[q * 4 + 3] * 0.35355339059327373f));
            *reinterpret_cast<ushort4*>(&hid_s[el][jb + q * 4]) = pk;
        }
    }
    __syncthreads();

    // ---- phase B: hid[64x64] @ Rw2T -> w_lds[64 slots][256] -------------------
    {
        short8 bfr[4][2];
#pragma unroll
        for (int t = 0; t < 4; t++)
#pragma unroll
            for (int s = 0; s < 2; s++)
                bfr[t][s] = *reinterpret_cast<const short8*>(
                    Rw2 + (long)(wv * 64 + t * 16 + llo) * 64 + s * 32 + lhi * 8);
        f32x4 acc[4][4];
#pragma unroll
        for (int i = 0; i < 4; i++)
#pragma unroll
            for (int t = 0; t < 4; t++) acc[i][t] = 0.0f;
#pragma unroll
        for (int s = 0; s < 2; s++) {
            short8 af[4];
#pragma unroll
            for (int i = 0; i < 4; i++)
                af[i] = *reinterpret_cast<const short8*>(&hid_s[i * 16 + llo][s * 32 + lhi * 8]);
#pragma unroll
            for (int i = 0; i < 4; i++)
#pragma unroll
                for (int t = 0; t < 4; t++)
                    acc[i][t] = __builtin_amdgcn_mfma_f32_16x16x32_bf16(af[i], bfr[t][s], acc[i][t], 0, 0, 0);
        }
        __syncthreads();     // all hid reads done; safe to overwrite region with w
#pragma unroll
        for (int i = 0; i < 4; i++)
#pragma unroll
            for (int t = 0; t < 4; t++)
#pragma unroll
                for (int r = 0; r < 4; r++)
                    w_lds[(i * 16 + lhi * 4 + r) * RROW + wv * 64 + t * 16 + llo] =
                        f2us(acc[i][t][r] * 0.125f);
    }
    __syncthreads();

    // ---- phase C: 16-deep h preload (SGPR base) + pk-bf16 atomic reduction ----
    {
        const float qn = 0.25f;                 // 1/sqrt(avg_neigh)
        const float rs3 = 0.57735026918962576f; // 1/sqrt(3)
        int l = lane;
        int base = wv * 16;

        ushort4 hreg[16];
#pragma unroll
        for (int ss = 0; ss < 16; ss++) {
            long sx = (long)__builtin_amdgcn_readfirstlane(meta_s[base + ss].x);
            hreg[ss] = *reinterpret_cast<const ushort4*>(h + sx * 256 + l * 4);
        }

        float acc[8];
#pragma unroll
        for (int r = 0; r < 8; r++) acc[r] = 0.f;
        int cur = -1;

#pragma unroll
        for (int ss = 0; ss < 16; ss++) {
            unsigned my = (unsigned)__builtin_amdgcn_readfirstlane(meta_s[base + ss].y);
            unsigned mz = (unsigned)__builtin_amdgcn_readfirstlane(meta_s[base + ss].z);
            unsigned mw = (unsigned)__builtin_amdgcn_readfirstlane(meta_s[base + ss].w);
            int node = (int)(mw >> 18);
            if (node != cur) {                       // wave-uniform branch (SCC)
                if (cur >= 0) {
                    u16* dst = abuf + (long)cur * 512 + l * 2;
                    atom_pk(dst,       acc[0] * qn, acc[1] * qn * rs3);
                    atom_pk(dst + 128, acc[2] * qn, acc[3] * qn);
                    atom_pk(dst + 256, acc[4] * qn, acc[5] * qn);
                    atom_pk(dst + 384, acc[6] * qn, acc[7] * qn);
                }
                cur = node;
#pragma unroll
                for (int r = 0; r < 8; r++) acc[r] = 0.f;
            }
            int sl = base + ss;
            float w0 = us2f(w_lds[sl * RROW + l]);
            float w1 = us2f(w_lds[sl * RROW + 64 + l]);
            float w2 = us2f(w_lds[sl * RROW + 128 + l]);
            float w3 = us2f(w_lds[sl * RROW + 192 + l]);
            float y0  = us2f_s(my & 0xffffu);       // SALU shift, SGPR operand
            float y1x = us2f_s(my >> 16);
            float y1y = us2f_s(mz & 0xffffu);
            float y1z = us2f_s(mz >> 16);
            float s0 = us2f(hreg[ss].x), s1x = us2f(hreg[ss].y);
            float s1y = us2f(hreg[ss].z), s1z = us2f(hreg[ss].w);
            acc[0] += w0 * s0 * y0;
            acc[1] += w1 * (s1x * y1x + s1y * y1y + s1z * y1z);
            acc[2] += w2 * s0 * y1x;  acc[3] += w3 * s1x * y0;
            acc[4] += w2 * s0 * y1y;  acc[5] += w3 * s1y * y0;
            acc[6] += w2 * s0 * y1z;  acc[7] += w3 * s1z * y0;
        }
        {
            u16* dst = abuf + (long)cur * 512 + l * 2;
            atom_pk(dst,       acc[0] * qn, acc[1] * qn * rs3);
            atom_pk(dst + 128, acc[2] * qn, acc[3] * qn);
            atom_pk(dst + 256, acc[4] * qn, acc[5] * qn);
            atom_pk(dst + 384, acc[6] * qn, acc[7] * qn);
        }
    }
}

// ---------------- linear_down + species sc + gate (MFMA) ------------------------
// Block = 32 nodes, 5 waves: wave g = output group {scal, gate, vx, vy, vz}.
// abuf is pair-interleaved bf16: A-fragments load directly as short8; the
// matching K-permutation is baked into c_Wd0/c_Wd1 (k' = chan*2 + part).
#define DN 32
__global__ void __launch_bounds__(320, 3)
k_down(const u16* __restrict__ abuf, const u16* __restrict__ x0,
       const u16* __restrict__ x1T, const int* __restrict__ species,
       const u16* __restrict__ Wd0T, const u16* __restrict__ Wd1T,
       const u16* __restrict__ Wsc0T, const u16* __restrict__ Wsc1T,
       float* __restrict__ out) {
    __shared__ float gate_s[DN][65];
    __shared__ float vec_s[DN * 192];       // raw f1 in output order [row][col*3+c]
    __shared__ int sp_s[DN];
    int tid = threadIdx.x;
    int g = tid >> 6;
    int lane = tid & 63, lhi = lane >> 4, llo = lane & 15;
    int node0 = blockIdx.x * DN;
    if (tid < DN) sp_s[tid] = species[node0 + tid];
    __syncthreads();

    const u16* Ad; const u16* BdT; int bcol;
    const u16* As; const u16* BsT; int sstr;
    if (g <= 1) { Ad = abuf; BdT = Wd0T; bcol = g * 64; As = x0; BsT = Wsc0T; sstr = 8192; }
    else        { Ad = abuf + (g - 1) * 128; BdT = Wd1T; bcol = 0;
                  As = x1T + (long)(g - 2) * N64; BsT = Wsc1T; sstr = 4096; }

    const float inv2 = 0.08838834764831845f;  // 1/sqrt(128)
    const float inv  = 0.125f;                // 1/sqrt(64)

    // ---- self-connection phase: all species, row-select -----------------------
    short8 a2[DN / 16][2];
#pragma unroll
    for (int rt = 0; rt < DN / 16; rt++)
#pragma unroll
        for (int ks = 0; ks < 2; ks++)
            a2[rt][ks] = *reinterpret_cast<const short8*>(
                As + (long)(node0 + rt * 16 + llo) * 64 + ks * 32 + lhi * 8);

    f32x4 res[DN / 16][4];
#pragma unroll
    for (int rt = 0; rt < DN / 16; rt++)
#pragma unroll
        for (int ct = 0; ct < 4; ct++) res[rt][ct] = 0.0f;

    for (int s = 0; s < 4; s++) {
        short8 bs[4][2];
#pragma unroll
        for (int ct = 0; ct < 4; ct++)
#pragma unroll
            for (int ks = 0; ks < 2; ks++)
                bs[ct][ks] = *reinterpret_cast<const short8*>(
                    BsT + (long)s * sstr + (long)(bcol + ct * 16 + llo) * 64 + ks * 32 + lhi * 8);
#pragma unroll
        for (int rt = 0; rt < DN / 16; rt++) {
            f32x4 accs[4];
#pragma unroll
            for (int ct = 0; ct < 4; ct++) accs[ct] = 0.0f;
#pragma unroll
            for (int ks = 0; ks < 2; ks++)
#pragma unroll
                for (int ct = 0; ct < 4; ct++)
                    accs[ct] = __builtin_amdgcn_mfma_f32_16x16x32_bf16(a2[rt][ks], bs[ct][ks], accs[ct], 0, 0, 0);
#pragma unroll
            for (int r = 0; r < 4; r++) {
                int sp = sp_s[rt * 16 + lhi * 4 + r];
                if (sp == s)
#pragma unroll
                    for (int ct = 0; ct < 4; ct++) res[rt][ct][r] = accs[ct][r];
            }
        }
    }

    // ---- linear_down phase -----------------------------------------------------
    short8 bd[4][4];
#pragma unroll
    for (int ct = 0; ct < 4; ct++)
#pragma unroll
        for (int ks = 0; ks < 4; ks++)
            bd[ct][ks] = *reinterpret_cast<const short8*>(
                BdT + (long)(bcol + ct * 16 + llo) * 128 + ks * 32 + lhi * 8);

#pragma unroll
    for (int rt = 0; rt < DN / 16; rt++) {
        f32x4 accd[4];
#pragma unroll
        for (int ct = 0; ct < 4; ct++) accd[ct] = 0.0f;
#pragma unroll
        for (int ks = 0; ks < 4; ks++) {
            short8 a = *reinterpret_cast<const short8*>(
                Ad + (long)(node0 + rt * 16 + llo) * 512 + ks * 32 + lhi * 8);
#pragma unroll
            for (int ct = 0; ct < 4; ct++)
                accd[ct] = __builtin_amdgcn_mfma_f32_16x16x32_bf16(a, bd[ct][ks], accd[ct], 0, 0, 0);
        }
#pragma unroll
        for (int ct = 0; ct < 4; ct++)
#pragma unroll
            for (int r = 0; r < 4; r++) {
                float fvv = 0.5f * (accd[ct][r] * inv2 + res[rt][ct][r] * inv);
                int row = rt * 16 + lhi * 4 + r;
                int col = ct * 16 + llo;
                if (g == 0) {
                    out[(long)(node0 + row) * 64 + col] = silu_f(fvv);
                } else if (g == 1) {
                    gate_s[row][col] = silu_f(fvv);
                } else {
                    vec_s[row * 192 + col * 3 + (g - 2)] = fvv;
                }
            }
    }
    __syncthreads();

    // ---- cooperative coalesced vector store (gate applied here) ---------------
    {
        float* vout = out + (long)N64 + (long)node0 * 192;
        for (int q4 = tid; q4 < DN * 48; q4 += 320) {
            int q = q4 * 4;
            int row = q4 / 48;                // 48 float4 per node row
            int rem = q - row * 192;
            f32x4 v = *reinterpret_cast<const f32x4*>(&vec_s[q]);
#pragma unroll
            for (int e = 0; e < 4; e++) v[e] *= gate_s[row][(rem + e) / 3];
            *reinterpret_cast<f32x4*>(vout + q) = v;
        }
    }
}

// ---------------- host launch --------------------------------------------------
extern "C" void kernel_launch(void* const* d_in, const int* in_sizes, int n_in,
                              void* d_out, int out_size, void* d_ws, size_t ws_size,
                              hipStream_t stream) {
    const int* senders   = (const int*)d_in[5];
    const int* receivers = (const int*)d_in[6];
    const int* species   = (const int*)d_in[7];
    float* out = (float*)d_out;

    char* ws = (char*)d_ws;
    size_t o = 0;
    auto alloc = [&](size_t bytes) { size_t p = o; o = (o + bytes + 255) & ~255UL; return p; };
    int* flag   = (int*)(ws + alloc(4));
    int* cnt    = (int*)(ws + alloc((size_t)NN * 4));
    int* offs   = (int*)(ws + alloc((size_t)(NN + 1) * 4));
    int* cursor = (int*)(ws + alloc((size_t)NN * 4));
    int4* meta  = (int4*)(ws + alloc((size_t)NE * 16));
    u16* c_x0   = (u16*)(ws + alloc(SB0 * 2));
    u16* x1T    = (u16*)(ws + alloc((size_t)3 * N64 * 2));
    u16* c_ey0  = (u16*)(ws + alloc((SB2 - SB1) * 2));
    u16* c_ey1  = (u16*)(ws + alloc((SB3 - SB2) * 2));
    u16* c_re   = (u16*)(ws + alloc((SB4 - SB3) * 2));
    u16* c_Wup0 = (u16*)(ws + alloc((SB5 - SB4) * 2));
    u16* c_Wup1 = (u16*)(ws + alloc((SB6 - SB5) * 2));
    u16* c_Rw1  = (u16*)(ws + alloc((SB7 - SB6) * 2));
    u16* c_Rw2  = (u16*)(ws + alloc((SB8 - SB7) * 2));
    u16* c_Wd0  = (u16*)(ws + alloc((SB9 - SB8) * 2));
    u16* c_Wd1  = (u16*)(ws + alloc((SB10 - SB9) * 2));
    u16* c_Wsc0 = (u16*)(ws + alloc((SB11 - SB10) * 2));
    u16* c_Wsc1 = (u16*)(ws + alloc((SB12 - SB11) * 2));
    u16* h      = (u16*)(ws + alloc((size_t)NN * 256 * 2));   // [node][64][4]
    u16* abuf   = (u16*)(ws + alloc((size_t)NN * 512 * 2));   // [node][4pair][64][2] bf16

    k_sniff<<<2048, 256, 0, stream>>>((const u16*)d_in[4], flag, cnt, (f32x4*)abuf);
    k_convert<<<2946, 256, 0, stream>>>(d_in[0], d_in[1], d_in[2], d_in[3], d_in[4],
        d_in[8], d_in[9], d_in[10], d_in[11], d_in[12], d_in[13], d_in[14], d_in[15],
        flag, receivers, cnt,
        c_x0, x1T, c_ey0, c_ey1, c_re,
        c_Wup0, c_Wup1, c_Rw1, c_Rw2, c_Wd0, c_Wd1, c_Wsc0, c_Wsc1);
    k_scan<<<1, 256, 0, stream>>>(cnt, offs, cursor);
    k_scatter<<<NE / 256, 256, 0, stream>>>(receivers, senders, c_ey0, c_ey1,
                                            cursor, meta);

    k_up_gemm<<<dim3(NN / 256, 4), 256, 0, stream>>>(c_x0, x1T, c_Wup0, c_Wup1, h);

    k_edge<<<NE / 64, 256, 0, stream>>>(c_re, c_Rw1, c_Rw2, meta, h, abuf);

    k_down<<<NN / DN, 320, 0, stream>>>(abuf, c_x0, x1T, species,
                                        c_Wd0, c_Wd1, c_Wsc0, c_Wsc1, out);
}